// Round 3
// baseline (10971.832 us; speedup 1.0000x reference)
//
#include <hip/hip_runtime.h>

// ============================================================================
// ENAS RNN scan + decode for MI355X (gfx950).  Round 6: persistent scan kernel
// with lean device barrier + L2-bypass coherent state.
//
// Round-5 post-mortem: split-K x4 gave only -15%; ~17us/level remains because
// every kernel boundary (384 of them) invalidates per-XCD L2 (weights
// re-fetched from LLC latency-bound) plus ~5-8us dispatch overhead.
// Round-4's coop failure was cg::grid.sync + full agent acquire fences
// (buffer_inv wipes L2 -- same pathology, worse).
//
// This round: ONE persistent cooperative kernel (189 blocks x 1024 thr, same
// kc4 x mquad4 split-K inner structure as round 5):
//   - weights: ordinary cached loads -> stay L2-resident across ALL levels.
//   - h state (hi|lo packed u32) + c0: agent-scope RELAXED atomic load/store
//     (sc0/sc1 -> bypass L1/L2, coherent at LLC). No invalidates needed.
//   - barrier: monotonic counter; each wave drains its own vmcnt (write-
//     through stores globally visible at retire), thread0 relaxed-atomic
//     arrive + relaxed spin with s_sleep. NO acquire fence, NO buffer_inv.
// Math bit-identical to round 5. Fallback to round-5 multi-launch if coop
// launch is rejected.
//
// MFMA 16x16x32 bf16 layouts (m89-verified):
//   A: lane holds A[m=lane&15][k=(lane>>4)*8 + j], j=0..7
//   B: lane holds B[k=(lane>>4)*8+j][n=lane&15]
//   C/D: col = lane&15, row = (lane>>4)*4 + reg
// ============================================================================

#define TPB 256            // helper kernels
#define STPB 1024          // scan blocks: 16 waves
#define GPB 189            // persistent grid (max level width = 3*NTILE)

#define Tt 64
#define Bb 64
#define Hh 1000
#define Ee 1000
#define Vv 10000
#define HP 1024                 // padded row stride for h buffers
#define SLOT (Bb * HP)          // elems per h slot
#define KW 2000                 // E + H (w_x* row length)
#define NTILE 63                // ceil(1000/16)

typedef unsigned short u16;
typedef unsigned long long u64;
typedef short bf16x8 __attribute__((ext_vector_type(8)));
typedef float f32x4 __attribute__((ext_vector_type(4)));

// ---- ws layout (bytes) ----
// hl (packed hi|lo u32): 12*SLOT*4 = 3,145,728 at ws+0
#define OFF_C0    3145728u     // c0 : 64*HP*4 = 262,144
#define OFF_OBF   3407872u     // obf: 4096*HP*2 (bf16 outputs for decode A)
                               // (first 64 B double as barrier counter during scan;
                               //  cvt_kernel overwrites them afterwards)
#define OFF_WC    11796480u
#define WC_WXH    0u           // bf16 w_xh  : 2e6*2 = 4,000,000
#define WC_WXC    4000000u     // bf16 w_xc  : 4,000,000
#define WC_WH     8000000u     // bf16 Wh    : 22,000,000
#define WC_WCC    30000000u    // bf16 Wc    : 22,000,000
#define WC_END    52000000u
#define WS_CACHED (OFF_WC + WC_END)   // 63,796,480

// outb (fp32 leaf sums, 4096*1024*4 = 16,777,216 B) lives at the start of
// d_out (163.8 MB fp32 output); consumed by cvt before decode writes d_out.
#define OUTB_BYTES 16777216u

__device__ __forceinline__ float bf2f(u16 u) {
  union { unsigned int i; float f; } c; c.i = ((unsigned int)u) << 16; return c.f;
}
__device__ __forceinline__ u16 f2bf(float f) {
  union { float f; unsigned int i; } c; c.f = f;
  unsigned int u = c.i + 0x7FFFu + ((c.i >> 16) & 1u);
  return (u16)(u >> 16);
}
// Sanitize: clamp to +-16, maps NaN -> -16 (fmaxf/fminf return non-NaN arg).
__device__ __forceinline__ float sanf(float x) {
  return fminf(fmaxf(x, -16.0f), 16.0f);
}
__device__ __forceinline__ f32x4 mfma16(bf16x8 a, bf16x8 b, f32x4 c) {
  return __builtin_amdgcn_mfma_f32_16x16x32_bf16(a, b, c, 0, 0, 0);
}
__device__ __forceinline__ bf16x8 ld8(const u16* p) { return *(const bf16x8*)p; }
__device__ __forceinline__ bf16x8 cvt8(const float* p) {
  float4 v0 = *(const float4*)p, v1 = *(const float4*)(p + 4);
  bf16x8 r;
  r[0] = (short)f2bf(sanf(v0.x)); r[1] = (short)f2bf(sanf(v0.y));
  r[2] = (short)f2bf(sanf(v0.z)); r[3] = (short)f2bf(sanf(v0.w));
  r[4] = (short)f2bf(sanf(v1.x)); r[5] = (short)f2bf(sanf(v1.y));
  r[6] = (short)f2bf(sanf(v1.z)); r[7] = (short)f2bf(sanf(v1.w));
  return r;
}
// B-fragment load: cached bf16 (ws) or in-register f32->bf16. Element offset.
template<bool CB>
__device__ __forceinline__ bf16x8 ldB(const void* base, size_t off) {
  if constexpr (CB) return *(const bf16x8*)((const u16*)base + off);
  else              return cvt8((const float*)base + off);
}

// Coherent (LLC) access helpers for mutable scan state.  Agent-scope RELAXED
// atomics compile to sc0/sc1-flagged global ops: bypass the non-coherent
// per-XCD L2, no cache-maintenance instructions emitted.
__device__ __forceinline__ void ldhl8(const unsigned* p, bf16x8& hi, bf16x8& lo) {
  u64* q = (u64*)p;   // 8B-aligned: element offsets are multiples of 8
  u64 w0 = __hip_atomic_load(q + 0, __ATOMIC_RELAXED, __HIP_MEMORY_SCOPE_AGENT);
  u64 w1 = __hip_atomic_load(q + 1, __ATOMIC_RELAXED, __HIP_MEMORY_SCOPE_AGENT);
  u64 w2 = __hip_atomic_load(q + 2, __ATOMIC_RELAXED, __HIP_MEMORY_SCOPE_AGENT);
  u64 w3 = __hip_atomic_load(q + 3, __ATOMIC_RELAXED, __HIP_MEMORY_SCOPE_AGENT);
  hi[0] = (short)(u16)(w0 >> 16); lo[0] = (short)(u16)w0;
  hi[1] = (short)(u16)(w0 >> 48); lo[1] = (short)(u16)(w0 >> 32);
  hi[2] = (short)(u16)(w1 >> 16); lo[2] = (short)(u16)w1;
  hi[3] = (short)(u16)(w1 >> 48); lo[3] = (short)(u16)(w1 >> 32);
  hi[4] = (short)(u16)(w2 >> 16); lo[4] = (short)(u16)w2;
  hi[5] = (short)(u16)(w2 >> 48); lo[5] = (short)(u16)(w2 >> 32);
  hi[6] = (short)(u16)(w3 >> 16); lo[6] = (short)(u16)w3;
  hi[7] = (short)(u16)(w3 >> 48); lo[7] = (short)(u16)(w3 >> 32);
}
__device__ __forceinline__ unsigned ldw(const unsigned* p) {
  return __hip_atomic_load((unsigned*)p, __ATOMIC_RELAXED, __HIP_MEMORY_SCOPE_AGENT);
}
__device__ __forceinline__ void stw(unsigned* p, unsigned v) {
  __hip_atomic_store(p, v, __ATOMIC_RELAXED, __HIP_MEMORY_SCOPE_AGENT);
}
__device__ __forceinline__ float ldf(const float* p) {
  return __hip_atomic_load((float*)p, __ATOMIC_RELAXED, __HIP_MEMORY_SCOPE_AGENT);
}
__device__ __forceinline__ void stf(float* p, float v) {
  __hip_atomic_store(p, v, __ATOMIC_RELAXED, __HIP_MEMORY_SCOPE_AGENT);
}

__device__ __forceinline__ float sigm(float x) { return 1.0f / (1.0f + __expf(-x)); }
__device__ __forceinline__ float tanh_(float x) {
  float e = __expf(-2.0f * fabsf(x));
  float t = (1.0f - e) / (1.0f + e);
  return x < 0.0f ? -t : t;
}
__device__ __forceinline__ float actf(int a, float x) {
  if (a == 0) return fmaxf(x, 0.0f);   // relu
  if (a == 1) return tanh_(x);         // tanh
  if (a == 2) return sigm(x);          // sigmoid
  return x;                            // identity
}

// Edge schedule, grouped by DAG level (positions 0..10).
// act: 0=relu 1=tanh 2=sigmoid 3=identity
__constant__ short g_e[11]    = {0, 1, 2, 3, 10, 4, 5, 6, 7, 8, 9};
__constant__ short g_src[11]  = {0, 0, 1, 1, 6, 2, 2, 3, 3, 4, 4};
__constant__ short g_dst[11]  = {1, 6, 2, 8, 7, 3, 9, 4, 10, 5, 11};
__constant__ short g_act[11]  = {0, 1, 0, 2, 1, 1, 0, 3, 1, 0, 2};
__constant__ short g_leaf[11] = {0, 0, 0, 1, 1, 0, 1, 0, 1, 1, 1};

// f32 -> sanitized bf16 (weight cache). n divisible by 4.
__global__ void __launch_bounds__(TPB) wcvt_kernel(const float* __restrict__ src,
                                                   u16* __restrict__ dst, int n) {
  int i = (blockIdx.x * TPB + threadIdx.x) * 4;
  if (i < n) {
    float4 v = *(const float4*)(src + i);
    dst[i + 0] = f2bf(sanf(v.x));
    dst[i + 1] = f2bf(sanf(v.y));
    dst[i + 2] = f2bf(sanf(v.z));
    dst[i + 3] = f2bf(sanf(v.w));
  }
}

// hidden [64,1000] f32 -> h slot 11 packed hi|lo (pads zeroed by memset).
__global__ void __launch_bounds__(TPB) stage_kernel(const float* __restrict__ hidden,
                                                    unsigned* __restrict__ hl) {
  int b = blockIdx.x;
  for (int k = threadIdx.x; k < Hh; k += TPB) {
    float x = sanf(hidden[b * Hh + k]);
    u16 h = f2bf(x);
    u16 l = f2bf(x - bf2f(h));
    hl[11 * SLOT + b * HP + k] = ((unsigned)h << 16) | l;
  }
}

// ---------------------------------------------------------------------------
// Lean grid barrier: monotonic counter, relaxed atomics only.  Each wave's
// own s_waitcnt vmcnt(0) is the release (write-through stores are globally
// visible at retire); NO acquire fence (h reads bypass caches anyway).
// ---------------------------------------------------------------------------
__device__ __forceinline__ void gbar(unsigned* cnt, unsigned tgt) {
  asm volatile("s_waitcnt vmcnt(0) lgkmcnt(0)" ::: "memory");
  __syncthreads();
  if (threadIdx.x == 0) {
    __hip_atomic_fetch_add(cnt, 1u, __ATOMIC_RELAXED, __HIP_MEMORY_SCOPE_AGENT);
    while (__hip_atomic_load(cnt, __ATOMIC_RELAXED, __HIP_MEMORY_SCOPE_AGENT) < tgt)
      __builtin_amdgcn_s_sleep(4);
  }
  __syncthreads();
  __builtin_amdgcn_sched_barrier(0);
  asm volatile("" ::: "memory");
}

// ---------------------------------------------------------------------------
// Per-level bodies.  1024 threads = 16 waves = kc (K-chunk, 4) x mquad (m, 4).
// Split-K partials reduced through 32 KB LDS, epilogue by kc==0 waves.
// ---------------------------------------------------------------------------
template<bool CB>
__device__ __forceinline__ void lev0_body(
    const int bid, const int t,
    const int* __restrict__ inputs, const float* __restrict__ emb,
    const void* __restrict__ wxh, const float* __restrict__ bxh,
    const void* __restrict__ wxc, const float* __restrict__ bxc,
    unsigned* __restrict__ hl, float* __restrict__ c0b,
    float (*red)[8][64])
{
  const int tid = threadIdx.x;
  const int lane = tid & 63, wave = tid >> 6;
  const int mquad = wave & 3, kc = wave >> 2;
  const int l15 = lane & 15, quad = lane >> 4;
  const int koff = quad * 8;

  const int n0 = bid * 16;                      // 63 tiles
  const int nrow = n0 + l15;
  const int ncl = nrow < Hh ? nrow : Hh - 1;
  const size_t wrow = (size_t)ncl * KW;
  const int mrow = mquad * 16 + l15;
  int ix = inputs[t * Bb + mrow];
  ix = ix < 0 ? 0 : (ix >= Vv ? Vv - 1 : ix);   // defensive clamp
  const float* px = emb + (size_t)ix * Ee;
  const unsigned* ph = hl + 11 * SLOT + (size_t)mrow * HP;

  const int cb = kc * 8;
  const int ce = (kc == 3) ? 31 : cb + 8;

  f32x4 ac = {0.f, 0.f, 0.f, 0.f}, ah = {0.f, 0.f, 0.f, 0.f};
  // phase 1: x part (k 0..999), A converted f32->bf16 in-register
  #pragma unroll 2
  for (int c = cb; c < ce; ++c) {
    int k = c * 32 + koff;
    bf16x8 a = cvt8(px + k);
    ac = mfma16(a, ldB<CB>(wxc, wrow + k), ac);
    ah = mfma16(a, ldB<CB>(wxh, wrow + k), ah);
  }
  if (kc == 3) { // tail: mask A (embedding row end); B row len 2000 -> in-bounds
    int k = 992 + koff;
    bf16x8 a = {0, 0, 0, 0, 0, 0, 0, 0};
    if (quad == 0) a = cvt8(px + k);
    ac = mfma16(a, ldB<CB>(wxc, wrow + k), ac);
    ah = mfma16(a, ldB<CB>(wxh, wrow + k), ah);
  }
  // phase 2: h_prev part (hi + lo), B cols 1000..1999
  #pragma unroll 2
  for (int c = cb; c < ce; ++c) {
    int k = c * 32 + koff;
    bf16x8 a0, a1; ldhl8(ph + k, a0, a1);
    bf16x8 b0 = ldB<CB>(wxc, wrow + 1000 + k), b1 = ldB<CB>(wxh, wrow + 1000 + k);
    ac = mfma16(a0, b0, ac); ac = mfma16(a1, b0, ac);
    ah = mfma16(a0, b1, ah); ah = mfma16(a1, b1, ah);
  }
  if (kc == 3) { // tail: A reads zeroed pad (safe); mask B (w_x* row end)
    int k = 992 + koff;
    bf16x8 a0, a1; ldhl8(ph + k, a0, a1);
    bf16x8 b0 = {0, 0, 0, 0, 0, 0, 0, 0}, b1 = {0, 0, 0, 0, 0, 0, 0, 0};
    if (quad == 0) { b0 = ldB<CB>(wxc, wrow + 1000 + k); b1 = ldB<CB>(wxh, wrow + 1000 + k); }
    ac = mfma16(a0, b0, ac); ac = mfma16(a1, b0, ac);
    ah = mfma16(a0, b1, ah); ah = mfma16(a1, b1, ah);
  }

  // split-K reduction through LDS
  #pragma unroll
  for (int r = 0; r < 4; ++r) {
    red[wave][r][lane]     = ac[r];
    red[wave][4 + r][lane] = ah[r];
  }
  __syncthreads();
  if (kc == 0) {
    #pragma unroll
    for (int p = 1; p < 4; ++p) {
      const int w2 = p * 4 + mquad;
      #pragma unroll
      for (int r = 0; r < 4; ++r) {
        ac[r] += red[w2][r][lane];
        ah[r] += red[w2][4 + r][lane];
      }
    }
    const int ne = n0 + l15;
    if (ne < Hh) {
      float bxcv = sanf(bxc[ne]), bxhv = sanf(bxh[ne]);
      #pragma unroll
      for (int r = 0; r < 4; ++r) {
        int me = mquad * 16 + quad * 4 + r;
        size_t idx = (size_t)me * HP + ne;
        float c0v = sigm(ac[r] + bxcv);
        unsigned wprev = ldw(hl + 11 * SLOT + idx);
        float hp = bf2f((u16)(wprev >> 16)) + bf2f((u16)(wprev & 0xFFFFu));
        float h0 = sanf(c0v * tanh_(ah[r] + bxhv) + (1.0f - c0v) * hp);
        stf(c0b + idx, c0v);
        u16 hb = f2bf(h0);
        u16 lb = f2bf(h0 - bf2f(hb));
        stw(hl + idx, ((unsigned)hb << 16) | lb);   // slot 0
      }
    }
  }
  __syncthreads();   // red reused by next phase body
}

template<bool CB>
__device__ __forceinline__ void edge_body(
    const int bid, const int e0, const int t,
    const void* __restrict__ Wh, const void* __restrict__ Wc,
    unsigned* __restrict__ hl, const float* __restrict__ c0b,
    float* __restrict__ outb, float (*red)[8][64])
{
  const int tid = threadIdx.x;
  const int lane = tid & 63, wave = tid >> 6;
  const int mquad = wave & 3, kc = wave >> 2;
  const int l15 = lane & 15, quad = lane >> 4;
  const int koff = quad * 8;

  const int er = bid / NTILE;
  const int e = e0 + er;
  const int n0 = (bid - er * NTILE) * 16;
  const int we = g_e[e], src = g_src[e], dst = g_dst[e];
  const int nrow = n0 + l15;
  const int ncl = nrow < Hh ? nrow : Hh - 1;
  const size_t wrow = (size_t)we * (Hh * Hh) + (size_t)ncl * Hh;
  const int mrow = mquad * 16 + l15;
  const unsigned* pa = hl + (size_t)src * SLOT + (size_t)mrow * HP;

  const int cb = kc * 8;
  const int ce = (kc == 3) ? 31 : cb + 8;

  f32x4 ac = {0.f, 0.f, 0.f, 0.f}, ah = {0.f, 0.f, 0.f, 0.f};
  #pragma unroll 2
  for (int c = cb; c < ce; ++c) {
    int k = c * 32 + koff;
    bf16x8 a0, a1; ldhl8(pa + k, a0, a1);
    bf16x8 b0 = ldB<CB>(Wc, wrow + k), b1 = ldB<CB>(Wh, wrow + k);
    ac = mfma16(a0, b0, ac); ac = mfma16(a1, b0, ac);
    ah = mfma16(a0, b1, ah); ah = mfma16(a1, b1, ah);
  }
  if (kc == 3) { // tail: A reads zeroed pad (safe); mask B (row end)
    int k = 992 + koff;
    bf16x8 a0, a1; ldhl8(pa + k, a0, a1);
    bf16x8 b0 = {0, 0, 0, 0, 0, 0, 0, 0}, b1 = {0, 0, 0, 0, 0, 0, 0, 0};
    if (quad == 0) { b0 = ldB<CB>(Wc, wrow + k); b1 = ldB<CB>(Wh, wrow + k); }
    ac = mfma16(a0, b0, ac); ac = mfma16(a1, b0, ac);
    ah = mfma16(a0, b1, ah); ah = mfma16(a1, b1, ah);
  }

  // split-K reduction through LDS
  #pragma unroll
  for (int r = 0; r < 4; ++r) {
    red[wave][r][lane]     = ac[r];
    red[wave][4 + r][lane] = ah[r];
  }
  __syncthreads();
  if (kc == 0) {
    #pragma unroll
    for (int p = 1; p < 4; ++p) {
      const int w2 = p * 4 + mquad;
      #pragma unroll
      for (int r = 0; r < 4; ++r) {
        ac[r] += red[w2][r][lane];
        ah[r] += red[w2][4 + r][lane];
      }
    }
    const int ne = n0 + l15;
    if (ne < Hh) {
      const int act = g_act[e], leaf = g_leaf[e];
      const unsigned* pi = hl + (size_t)src * SLOT;
      unsigned* pj = hl + (size_t)dst * SLOT;
      #pragma unroll
      for (int r = 0; r < 4; ++r) {
        int me = mquad * 16 + quad * 4 + r;
        size_t idx = (size_t)me * HP + ne;
        float cj = sigm(ac[r]);
        float av = actf(act, ah[r]);
        unsigned wi = ldw(pi + idx);
        float hi_v = bf2f((u16)(wi >> 16)) + bf2f((u16)(wi & 0xFFFFu));
        float hj = sanf(cj * av + (1.0f - ldf(c0b + idx)) * hi_v);  // blend uses c0 (!)
        u16 hb = f2bf(hj);
        u16 lb = f2bf(hj - bf2f(hb));
        stw(pj + idx, ((unsigned)hb << 16) | lb);
        if (leaf) atomicAdd(outb + (size_t)(t * Bb + me) * HP + ne, hj);
      }
    }
  }
  __syncthreads();   // red reused by next phase body
}

// ---------------------------------------------------------------------------
// Persistent cooperative scan: all 64 timesteps, 6 gbar-separated phases each.
// ---------------------------------------------------------------------------
template<bool CB>
__global__ void __launch_bounds__(STPB) scan_kernel(
    const int* __restrict__ inputs, const float* __restrict__ emb,
    const void* __restrict__ wxh, const float* __restrict__ bxh,
    const void* __restrict__ wxc, const float* __restrict__ bxc,
    const void* __restrict__ Wh, const void* __restrict__ Wc,
    unsigned* __restrict__ hl, float* __restrict__ c0b,
    float* __restrict__ outb, unsigned* __restrict__ cnt)
{
  __shared__ float red[16][8][64];      // 32 KB
  const int bid = blockIdx.x;
  unsigned tgt = 0;

  for (int t = 0; t < Tt; ++t) {
    if (bid < NTILE)
      lev0_body<CB>(bid, t, inputs, emb, wxh, bxh, wxc, bxc, hl, c0b, red);
    tgt += GPB; gbar(cnt, tgt);
    if (bid < 2 * NTILE) edge_body<CB>(bid, 0, t, Wh, Wc, hl, c0b, outb, red);
    tgt += GPB; gbar(cnt, tgt);
    if (bid < 3 * NTILE) edge_body<CB>(bid, 2, t, Wh, Wc, hl, c0b, outb, red);
    tgt += GPB; gbar(cnt, tgt);
    if (bid < 2 * NTILE) edge_body<CB>(bid, 5, t, Wh, Wc, hl, c0b, outb, red);
    tgt += GPB; gbar(cnt, tgt);
    if (bid < 2 * NTILE) edge_body<CB>(bid, 7, t, Wh, Wc, hl, c0b, outb, red);
    tgt += GPB; gbar(cnt, tgt);
    if (bid < 2 * NTILE) edge_body<CB>(bid, 9, t, Wh, Wc, hl, c0b, outb, red);
    tgt += GPB; gbar(cnt, tgt);
  }
}

// ---------------------------------------------------------------------------
// Fallback multi-launch kernels (round-5 behavior; kernel boundary = sync).
// ---------------------------------------------------------------------------
template<bool CB>
__global__ void __launch_bounds__(STPB) lev0_kernel(
    int t, const int* __restrict__ inputs, const float* __restrict__ emb,
    const void* __restrict__ wxh, const float* __restrict__ bxh,
    const void* __restrict__ wxc, const float* __restrict__ bxc,
    unsigned* __restrict__ hl, float* __restrict__ c0b)
{
  __shared__ float red[16][8][64];
  lev0_body<CB>(blockIdx.x, t, inputs, emb, wxh, bxh, wxc, bxc, hl, c0b, red);
}

template<bool CB>
__global__ void __launch_bounds__(STPB) edge_kernel(
    int e0, int t, const void* __restrict__ Wh, const void* __restrict__ Wc,
    unsigned* __restrict__ hl, const float* __restrict__ c0b,
    float* __restrict__ outb)
{
  __shared__ float red[16][8][64];
  edge_body<CB>(blockIdx.x, e0, t, Wh, Wc, hl, c0b, outb, red);
}

// fp32 leaf sums (in d_out) -> bf16 * (1/6) into ws.obf; pads stay zero.
__global__ void __launch_bounds__(TPB) cvt_kernel(const float* __restrict__ outb,
                                                  u16* __restrict__ obf) {
  size_t i = ((size_t)blockIdx.x * TPB + threadIdx.x) * 4;
  float4 v = *(const float4*)(outb + i);
  const float s = 1.0f / 6.0f;
  obf[i + 0] = f2bf(sanf(v.x * s));
  obf[i + 1] = f2bf(sanf(v.y * s));
  obf[i + 2] = f2bf(sanf(v.z * s));
  obf[i + 3] = f2bf(sanf(v.w * s));
}

// decoded[4096,10000] = out @ dec_w.T + dec_b, f32 out. 64x64 tile per WG.
__global__ void __launch_bounds__(TPB) decode_kernel(
    const u16* __restrict__ obf, const float* __restrict__ decw,
    const float* __restrict__ decb, float* __restrict__ out)
{
  const int tid = threadIdx.x;
  const int lane = tid & 63, wave = tid >> 6;
  const int l15 = lane & 15, quad = lane >> 4;
  const int bm = blockIdx.x % 64;   // consecutive blocks share bn -> B reuse in L2
  const int bn = blockIdx.x / 64;
  const int mrow = bm * 64 + wave * 16 + l15;
  const u16* pa = obf + (size_t)mrow * HP;
  const float* pb[4];
  #pragma unroll
  for (int j = 0; j < 4; ++j) {
    int v = bn * 64 + j * 16 + l15;
    if (v > Vv - 1) v = Vv - 1;
    pb[j] = decw + (size_t)v * Hh;
  }
  f32x4 acc[4];
  #pragma unroll
  for (int j = 0; j < 4; ++j) acc[j] = (f32x4){0.f, 0.f, 0.f, 0.f};
  const int koff = quad * 8;
  #pragma unroll 2
  for (int c = 0; c < 31; ++c) {
    int k = c * 32 + koff;
    bf16x8 a = ld8(pa + k);
    #pragma unroll
    for (int j = 0; j < 4; ++j) acc[j] = mfma16(a, cvt8(pb[j] + k), acc[j]);
  }
  { // tail: A covers zeroed pads (in-bounds); mask B (dec_w row end)
    int k = 992 + koff;
    bf16x8 a = ld8(pa + k);
    bf16x8 z = {0, 0, 0, 0, 0, 0, 0, 0};
    #pragma unroll
    for (int j = 0; j < 4; ++j) {
      bf16x8 b = z;
      if (quad == 0) b = cvt8(pb[j] + k);
      acc[j] = mfma16(a, b, acc[j]);
    }
  }
  #pragma unroll
  for (int j = 0; j < 4; ++j) {
    int ne = bn * 64 + j * 16 + l15;
    if (ne < Vv) {
      float bv = sanf(decb[ne]);
      #pragma unroll
      for (int r = 0; r < 4; ++r) {
        int me = bm * 64 + wave * 16 + quad * 4 + r;
        out[(size_t)me * Vv + ne] = acc[j][r] + bv;
      }
    }
  }
}

extern "C" void kernel_launch(void* const* d_in, const int* in_sizes, int n_in,
                              void* d_out, int out_size, void* d_ws, size_t ws_size,
                              hipStream_t stream) {
  const int*   inputs = (const int*)d_in[0];
  const float* hidden = (const float*)d_in[1];
  const float* emb    = (const float*)d_in[2];
  const float* wxh    = (const float*)d_in[3];
  const float* bxh    = (const float*)d_in[4];
  const float* wxc    = (const float*)d_in[5];
  const float* bxc    = (const float*)d_in[6];
  const float* Wh     = (const float*)d_in[7];
  const float* Wc     = (const float*)d_in[8];
  const float* decw   = (const float*)d_in[9];
  const float* decb   = (const float*)d_in[10];

  char* ws = (char*)d_ws;
  unsigned* hl  = (unsigned*)(ws);
  float*    c0b = (float*)(ws + OFF_C0);
  u16*      obf = (u16*)(ws + OFF_OBF);
  unsigned* cnt = (unsigned*)(ws + OFF_OBF);  // overwritten by cvt afterwards
  float*    outb = (float*)d_out;   // fp32 leaf sums, consumed before decode

  const bool cached = (ws_size >= (size_t)WS_CACHED);
  u16* wxhb = (u16*)(ws + OFF_WC + WC_WXH);
  u16* wxcb = (u16*)(ws + OFF_WC + WC_WXC);
  u16* Whb  = (u16*)(ws + OFF_WC + WC_WH);
  u16* Wcb  = (u16*)(ws + OFF_WC + WC_WCC);

  // zero hl (pads must be 0) + c0 + barrier counter, and leaf-sum region
  hipMemsetAsync(ws, 0, OFF_OBF, stream);
  hipMemsetAsync(ws + OFF_OBF, 0, 256, stream);
  hipMemsetAsync(d_out, 0, OUTB_BYTES, stream);

  if (cached) {
    wcvt_kernel<<<(2000000 / 4 + TPB - 1) / TPB, TPB, 0, stream>>>(wxh, wxhb, 2000000);
    wcvt_kernel<<<(2000000 / 4 + TPB - 1) / TPB, TPB, 0, stream>>>(wxc, wxcb, 2000000);
    wcvt_kernel<<<(11000000 / 4 + TPB - 1) / TPB, TPB, 0, stream>>>(Wh, Whb, 11000000);
    wcvt_kernel<<<(11000000 / 4 + TPB - 1) / TPB, TPB, 0, stream>>>(Wc, Wcb, 11000000);
  }
  stage_kernel<<<Bb, TPB, 0, stream>>>(hidden, hl);

  const void* a_wxh = cached ? (const void*)wxhb : (const void*)wxh;
  const void* a_wxc = cached ? (const void*)wxcb : (const void*)wxc;
  const void* a_Wh  = cached ? (const void*)Whb  : (const void*)Wh;
  const void* a_Wc  = cached ? (const void*)Wcb  : (const void*)Wc;
  void* ka[12] = {(void*)&inputs, (void*)&emb, (void*)&a_wxh, (void*)&bxh,
                  (void*)&a_wxc, (void*)&bxc, (void*)&a_Wh, (void*)&a_Wc,
                  (void*)&hl, (void*)&c0b, (void*)&outb, (void*)&cnt};
  dim3 sgrid(GPB), sblk(STPB);
  hipError_t ce = cached
    ? hipLaunchCooperativeKernel(scan_kernel<true>,  sgrid, sblk, ka, 0, stream)
    : hipLaunchCooperativeKernel(scan_kernel<false>, sgrid, sblk, ka, 0, stream);

  if (ce != hipSuccess) {
    (void)hipGetLastError();   // clear sticky error; fall back to multi-launch
    static const int lev_off[5] = {0, 2, 5, 7, 9};
    static const int lev_cnt[5] = {2, 3, 2, 2, 2};
    for (int t = 0; t < Tt; ++t) {
      if (cached) {
        lev0_kernel<true><<<NTILE, STPB, 0, stream>>>(t, inputs, emb, wxhb, bxh,
                                                      wxcb, bxc, hl, c0b);
        for (int lev = 0; lev < 5; ++lev)
          edge_kernel<true><<<lev_cnt[lev] * NTILE, STPB, 0, stream>>>(
              lev_off[lev], t, Whb, Wcb, hl, c0b, outb);
      } else {
        lev0_kernel<false><<<NTILE, STPB, 0, stream>>>(t, inputs, emb, wxh, bxh,
                                                       wxc, bxc, hl, c0b);
        for (int lev = 0; lev < 5; ++lev)
          edge_kernel<false><<<lev_cnt[lev] * NTILE, STPB, 0, stream>>>(
              lev_off[lev], t, Wh, Wc, hl, c0b, outb);
      }
    }
  }

  cvt_kernel<<<(Tt * Bb * HP) / (TPB * 4), TPB, 0, stream>>>(outb, obf);
  decode_kernel<<<64 * 157, TPB, 0, stream>>>(obf, decw, decb, (float*)d_out);
}

// Round 5
// 7279.144 us; speedup vs baseline: 1.5073x; 1.5073x over previous
//
#include <hip/hip_runtime.h>

// ============================================================================
// ENAS RNN scan + decode for MI355X (gfx950).  Round 8: round-7 design with
// the inline-asm early-clobber fix.
//
// Round-7 post-mortem: crash was the ldhl8 asm -- two "=v" outputs without
// early-clobber let the RA overlap output registers with the second load's
// address pair; first load corrupted the address -> wild access -> abort.
// Fix: "=&v".  Everything else is round-7's (sound) design:
//   - persistent coop kernel, weights L2-resident across all 384 levels.
//   - contention-free barrier: distinct 64B arrival slots (plain atomic
//     stores), master block's lanes spin one-slot-each, single release word.
//   - h state: coalesced global_load_dwordx4 sc0 sc1 (LLC-coherent bypass);
//     atomic-store producer side (round-6-proven visibility path).
//   - B weight loads issued before the A-asm so their latency hides under
//     the asm's vmcnt(0).
// Fallback to multi-launch (round-5 winner) if coop launch is rejected.
//
// MFMA 16x16x32 bf16 layouts (m89-verified):
//   A: lane holds A[m=lane&15][k=(lane>>4)*8 + j], j=0..7
//   B: lane holds B[k=(lane>>4)*8+j][n=lane&15]
//   C/D: col = lane&15, row = (lane>>4)*4 + reg
// ============================================================================

#define TPB 256            // helper kernels
#define STPB 1024          // scan blocks: 16 waves
#define GPB 189            // persistent grid (max level width = 3*NTILE)

#define Tt 64
#define Bb 64
#define Hh 1000
#define Ee 1000
#define Vv 10000
#define HP 1024                 // padded row stride for h buffers
#define SLOT (Bb * HP)          // elems per h slot
#define KW 2000                 // E + H (w_x* row length)
#define NTILE 63                // ceil(1000/16)

typedef unsigned short u16;
typedef unsigned long long u64;
typedef short bf16x8 __attribute__((ext_vector_type(8)));
typedef float f32x4 __attribute__((ext_vector_type(4)));
typedef unsigned u32x4 __attribute__((ext_vector_type(4)));

// ---- ws layout (bytes) ----
// hl (packed hi|lo u32): 12*SLOT*4 = 3,145,728 at ws+0
#define OFF_C0    3145728u     // c0 : 64*HP*4 = 262,144
#define OFF_OBF   3407872u     // obf: 4096*HP*2 (bf16 outputs for decode A)
                               // (first 32 KB double as barrier arr/rel during
                               //  scan; cvt_kernel overwrites them afterwards)
#define OFF_WC    11796480u
#define WC_WXH    0u           // bf16 w_xh  : 2e6*2 = 4,000,000
#define WC_WXC    4000000u     // bf16 w_xc  : 4,000,000
#define WC_WH     8000000u     // bf16 Wh    : 22,000,000
#define WC_WCC    30000000u    // bf16 Wc    : 22,000,000
#define WC_END    52000000u
#define WS_CACHED (OFF_WC + WC_END)   // 63,796,480

#define REL_OFF   (16384u / 4u)       // rel word, u32 index from arr base

// outb (fp32 leaf sums, 4096*1024*4 = 16,777,216 B) lives at the start of
// d_out (163.8 MB fp32 output); consumed by cvt before decode writes d_out.
#define OUTB_BYTES 16777216u

__device__ __forceinline__ float bf2f(u16 u) {
  union { unsigned int i; float f; } c; c.i = ((unsigned int)u) << 16; return c.f;
}
__device__ __forceinline__ u16 f2bf(float f) {
  union { float f; unsigned int i; } c; c.f = f;
  unsigned int u = c.i + 0x7FFFu + ((c.i >> 16) & 1u);
  return (u16)(u >> 16);
}
// Sanitize: clamp to +-16, maps NaN -> -16 (fmaxf/fminf return non-NaN arg).
__device__ __forceinline__ float sanf(float x) {
  return fminf(fmaxf(x, -16.0f), 16.0f);
}
__device__ __forceinline__ f32x4 mfma16(bf16x8 a, bf16x8 b, f32x4 c) {
  return __builtin_amdgcn_mfma_f32_16x16x32_bf16(a, b, c, 0, 0, 0);
}
__device__ __forceinline__ bf16x8 ld8(const u16* p) { return *(const bf16x8*)p; }
__device__ __forceinline__ bf16x8 cvt8(const float* p) {
  float4 v0 = *(const float4*)p, v1 = *(const float4*)(p + 4);
  bf16x8 r;
  r[0] = (short)f2bf(sanf(v0.x)); r[1] = (short)f2bf(sanf(v0.y));
  r[2] = (short)f2bf(sanf(v0.z)); r[3] = (short)f2bf(sanf(v0.w));
  r[4] = (short)f2bf(sanf(v1.x)); r[5] = (short)f2bf(sanf(v1.y));
  r[6] = (short)f2bf(sanf(v1.z)); r[7] = (short)f2bf(sanf(v1.w));
  return r;
}
// B-fragment load: cached bf16 (ws) or in-register f32->bf16. Element offset.
template<bool CB>
__device__ __forceinline__ bf16x8 ldB(const void* base, size_t off) {
  if constexpr (CB) return *(const bf16x8*)((const u16*)base + off);
  else              return cvt8((const float*)base + off);
}

// ---- coherent (LLC) access for mutable scan state ----
// Loads: dwordx4 with sc0 sc1 (bypass L1+L2, read at LLC).  "=&v" early-
// clobber is REQUIRED: outputs are written by load 1 before load 2 consumes
// its address operand.
// Stores: agent-scope relaxed atomics (LLC-visible once vmcnt=0) -- the
// round-6-proven path.
__device__ __forceinline__ void ldhl8(const unsigned* p, bf16x8& hi, bf16x8& lo) {
  u32x4 a, b;
  asm volatile("global_load_dwordx4 %0, %2, off sc0 sc1\n\t"
               "global_load_dwordx4 %1, %3, off sc0 sc1\n\t"
               "s_waitcnt vmcnt(0)"
               : "=&v"(a), "=&v"(b)
               : "v"(p), "v"(p + 4));
  hi[0] = (short)(u16)(a[0] >> 16); lo[0] = (short)(u16)a[0];
  hi[1] = (short)(u16)(a[1] >> 16); lo[1] = (short)(u16)a[1];
  hi[2] = (short)(u16)(a[2] >> 16); lo[2] = (short)(u16)a[2];
  hi[3] = (short)(u16)(a[3] >> 16); lo[3] = (short)(u16)a[3];
  hi[4] = (short)(u16)(b[0] >> 16); lo[4] = (short)(u16)b[0];
  hi[5] = (short)(u16)(b[1] >> 16); lo[5] = (short)(u16)b[1];
  hi[6] = (short)(u16)(b[2] >> 16); lo[6] = (short)(u16)b[2];
  hi[7] = (short)(u16)(b[3] >> 16); lo[7] = (short)(u16)b[3];
}
__device__ __forceinline__ unsigned ldw(const unsigned* p) {
  return __hip_atomic_load((unsigned*)p, __ATOMIC_RELAXED, __HIP_MEMORY_SCOPE_AGENT);
}
__device__ __forceinline__ void stw(unsigned* p, unsigned v) {
  __hip_atomic_store(p, v, __ATOMIC_RELAXED, __HIP_MEMORY_SCOPE_AGENT);
}
__device__ __forceinline__ float ldf(const float* p) {
  return __hip_atomic_load((float*)p, __ATOMIC_RELAXED, __HIP_MEMORY_SCOPE_AGENT);
}
__device__ __forceinline__ void stf(float* p, float v) {
  __hip_atomic_store(p, v, __ATOMIC_RELAXED, __HIP_MEMORY_SCOPE_AGENT);
}

__device__ __forceinline__ float sigm(float x) { return 1.0f / (1.0f + __expf(-x)); }
__device__ __forceinline__ float tanh_(float x) {
  float e = __expf(-2.0f * fabsf(x));
  float t = (1.0f - e) / (1.0f + e);
  return x < 0.0f ? -t : t;
}
__device__ __forceinline__ float actf(int a, float x) {
  if (a == 0) return fmaxf(x, 0.0f);   // relu
  if (a == 1) return tanh_(x);         // tanh
  if (a == 2) return sigm(x);          // sigmoid
  return x;                            // identity
}

// Edge schedule, grouped by DAG level (positions 0..10).
// act: 0=relu 1=tanh 2=sigmoid 3=identity
__constant__ short g_e[11]    = {0, 1, 2, 3, 10, 4, 5, 6, 7, 8, 9};
__constant__ short g_src[11]  = {0, 0, 1, 1, 6, 2, 2, 3, 3, 4, 4};
__constant__ short g_dst[11]  = {1, 6, 2, 8, 7, 3, 9, 4, 10, 5, 11};
__constant__ short g_act[11]  = {0, 1, 0, 2, 1, 1, 0, 3, 1, 0, 2};
__constant__ short g_leaf[11] = {0, 0, 0, 1, 1, 0, 1, 0, 1, 1, 1};

// f32 -> sanitized bf16 (weight cache). n divisible by 4.
__global__ void __launch_bounds__(TPB) wcvt_kernel(const float* __restrict__ src,
                                                   u16* __restrict__ dst, int n) {
  int i = (blockIdx.x * TPB + threadIdx.x) * 4;
  if (i < n) {
    float4 v = *(const float4*)(src + i);
    dst[i + 0] = f2bf(sanf(v.x));
    dst[i + 1] = f2bf(sanf(v.y));
    dst[i + 2] = f2bf(sanf(v.z));
    dst[i + 3] = f2bf(sanf(v.w));
  }
}

// hidden [64,1000] f32 -> h slot 11 packed hi|lo (pads zeroed by memset).
__global__ void __launch_bounds__(TPB) stage_kernel(const float* __restrict__ hidden,
                                                    unsigned* __restrict__ hl) {
  int b = blockIdx.x;
  for (int k = threadIdx.x; k < Hh; k += TPB) {
    float x = sanf(hidden[b * Hh + k]);
    u16 h = f2bf(x);
    u16 l = f2bf(x - bf2f(h));
    hl[11 * SLOT + b * HP + k] = ((unsigned)h << 16) | l;
  }
}

// ---------------------------------------------------------------------------
// Contention-free grid barrier.
//   arr: one u32 slot per block, stride 16 u32 (64 B) -- arrivals, no RMW.
//   rel: single release word written by master (block 0) after it has
//        observed every arrival (master's lanes spin one-slot-each).
// Release = each wave's own vmcnt(0) drain before arrive (sc1 stores are
// LLC-visible once retired).  No cache-maintenance instructions anywhere.
// ---------------------------------------------------------------------------
__device__ __forceinline__ void gbar(unsigned* arr, unsigned ep) {
  asm volatile("s_waitcnt vmcnt(0) lgkmcnt(0)" ::: "memory");
  __syncthreads();
  const int tid = threadIdx.x;
  if (blockIdx.x == 0) {
    if (tid >= 1 && tid < GPB) {
      while (ldw(arr + tid * 16) < ep) __builtin_amdgcn_s_sleep(2);
    }
    __syncthreads();
    if (tid == 0) stw(arr + REL_OFF, ep);
  } else {
    if (tid == 0) {
      stw(arr + blockIdx.x * 16, ep);
      while (ldw(arr + REL_OFF) < ep) __builtin_amdgcn_s_sleep(2);
    }
    __syncthreads();
  }
  __builtin_amdgcn_sched_barrier(0);
  asm volatile("" ::: "memory");
}

// ---------------------------------------------------------------------------
// Per-level bodies.  1024 threads = 16 waves = kc (K-chunk, 4) x mquad (m, 4).
// Split-K partials reduced through 32 KB LDS, epilogue by kc==0 waves.
// B loads issued before the A-asm so weight latency hides under its vmcnt(0).
// ---------------------------------------------------------------------------
template<bool CB>
__device__ __forceinline__ void lev0_body(
    const int bid, const int t,
    const int* __restrict__ inputs, const float* __restrict__ emb,
    const void* __restrict__ wxh, const float* __restrict__ bxh,
    const void* __restrict__ wxc, const float* __restrict__ bxc,
    unsigned* __restrict__ hl, float* __restrict__ c0b,
    float (*red)[8][64])
{
  const int tid = threadIdx.x;
  const int lane = tid & 63, wave = tid >> 6;
  const int mquad = wave & 3, kc = wave >> 2;
  const int l15 = lane & 15, quad = lane >> 4;
  const int koff = quad * 8;

  const int n0 = bid * 16;                      // 63 tiles
  const int nrow = n0 + l15;
  const int ncl = nrow < Hh ? nrow : Hh - 1;
  const size_t wrow = (size_t)ncl * KW;
  const int mrow = mquad * 16 + l15;
  int ix = inputs[t * Bb + mrow];
  ix = ix < 0 ? 0 : (ix >= Vv ? Vv - 1 : ix);   // defensive clamp
  const float* px = emb + (size_t)ix * Ee;
  const unsigned* ph = hl + 11 * SLOT + (size_t)mrow * HP;

  const int cb = kc * 8;
  const int ce = (kc == 3) ? 31 : cb + 8;

  f32x4 ac = {0.f, 0.f, 0.f, 0.f}, ah = {0.f, 0.f, 0.f, 0.f};
  // phase 1: x part (k 0..999), A converted f32->bf16 in-register
  #pragma unroll 2
  for (int c = cb; c < ce; ++c) {
    int k = c * 32 + koff;
    bf16x8 a = cvt8(px + k);
    ac = mfma16(a, ldB<CB>(wxc, wrow + k), ac);
    ah = mfma16(a, ldB<CB>(wxh, wrow + k), ah);
  }
  if (kc == 3) { // tail: mask A (embedding row end); B row len 2000 -> in-bounds
    int k = 992 + koff;
    bf16x8 a = {0, 0, 0, 0, 0, 0, 0, 0};
    if (quad == 0) a = cvt8(px + k);
    ac = mfma16(a, ldB<CB>(wxc, wrow + k), ac);
    ah = mfma16(a, ldB<CB>(wxh, wrow + k), ah);
  }
  // phase 2: h_prev part (hi + lo), B cols 1000..1999
  #pragma unroll 2
  for (int c = cb; c < ce; ++c) {
    int k = c * 32 + koff;
    bf16x8 b0 = ldB<CB>(wxc, wrow + 1000 + k), b1 = ldB<CB>(wxh, wrow + 1000 + k);
    bf16x8 a0, a1; ldhl8(ph + k, a0, a1);
    ac = mfma16(a0, b0, ac); ac = mfma16(a1, b0, ac);
    ah = mfma16(a0, b1, ah); ah = mfma16(a1, b1, ah);
  }
  if (kc == 3) { // tail: A reads zeroed pad (safe); mask B (w_x* row end)
    int k = 992 + koff;
    bf16x8 b0 = {0, 0, 0, 0, 0, 0, 0, 0}, b1 = {0, 0, 0, 0, 0, 0, 0, 0};
    if (quad == 0) { b0 = ldB<CB>(wxc, wrow + 1000 + k); b1 = ldB<CB>(wxh, wrow + 1000 + k); }
    bf16x8 a0, a1; ldhl8(ph + k, a0, a1);
    ac = mfma16(a0, b0, ac); ac = mfma16(a1, b0, ac);
    ah = mfma16(a0, b1, ah); ah = mfma16(a1, b1, ah);
  }

  // split-K reduction through LDS
  #pragma unroll
  for (int r = 0; r < 4; ++r) {
    red[wave][r][lane]     = ac[r];
    red[wave][4 + r][lane] = ah[r];
  }
  __syncthreads();
  if (kc == 0) {
    #pragma unroll
    for (int p = 1; p < 4; ++p) {
      const int w2 = p * 4 + mquad;
      #pragma unroll
      for (int r = 0; r < 4; ++r) {
        ac[r] += red[w2][r][lane];
        ah[r] += red[w2][4 + r][lane];
      }
    }
    const int ne = n0 + l15;
    if (ne < Hh) {
      float bxcv = sanf(bxc[ne]), bxhv = sanf(bxh[ne]);
      #pragma unroll
      for (int r = 0; r < 4; ++r) {
        int me = mquad * 16 + quad * 4 + r;
        size_t idx = (size_t)me * HP + ne;
        float c0v = sigm(ac[r] + bxcv);
        unsigned wprev = ldw(hl + 11 * SLOT + idx);
        float hp = bf2f((u16)(wprev >> 16)) + bf2f((u16)(wprev & 0xFFFFu));
        float h0 = sanf(c0v * tanh_(ah[r] + bxhv) + (1.0f - c0v) * hp);
        stf(c0b + idx, c0v);
        u16 hb = f2bf(h0);
        u16 lb = f2bf(h0 - bf2f(hb));
        stw(hl + idx, ((unsigned)hb << 16) | lb);   // slot 0
      }
    }
  }
}

template<bool CB>
__device__ __forceinline__ void edge_body(
    const int bid, const int e0, const int t,
    const void* __restrict__ Wh, const void* __restrict__ Wc,
    unsigned* __restrict__ hl, const float* __restrict__ c0b,
    float* __restrict__ outb, float (*red)[8][64])
{
  const int tid = threadIdx.x;
  const int lane = tid & 63, wave = tid >> 6;
  const int mquad = wave & 3, kc = wave >> 2;
  const int l15 = lane & 15, quad = lane >> 4;
  const int koff = quad * 8;

  const int er = bid / NTILE;
  const int e = e0 + er;
  const int n0 = (bid - er * NTILE) * 16;
  const int we = g_e[e], src = g_src[e], dst = g_dst[e];
  const int nrow = n0 + l15;
  const int ncl = nrow < Hh ? nrow : Hh - 1;
  const size_t wrow = (size_t)we * (Hh * Hh) + (size_t)ncl * Hh;
  const int mrow = mquad * 16 + l15;
  const unsigned* pa = hl + (size_t)src * SLOT + (size_t)mrow * HP;

  const int cb = kc * 8;
  const int ce = (kc == 3) ? 31 : cb + 8;

  f32x4 ac = {0.f, 0.f, 0.f, 0.f}, ah = {0.f, 0.f, 0.f, 0.f};
  #pragma unroll 2
  for (int c = cb; c < ce; ++c) {
    int k = c * 32 + koff;
    bf16x8 b0 = ldB<CB>(Wc, wrow + k), b1 = ldB<CB>(Wh, wrow + k);
    bf16x8 a0, a1; ldhl8(pa + k, a0, a1);
    ac = mfma16(a0, b0, ac); ac = mfma16(a1, b0, ac);
    ah = mfma16(a0, b1, ah); ah = mfma16(a1, b1, ah);
  }
  if (kc == 3) { // tail: A reads zeroed pad (safe); mask B (row end)
    int k = 992 + koff;
    bf16x8 b0 = {0, 0, 0, 0, 0, 0, 0, 0}, b1 = {0, 0, 0, 0, 0, 0, 0, 0};
    if (quad == 0) { b0 = ldB<CB>(Wc, wrow + k); b1 = ldB<CB>(Wh, wrow + k); }
    bf16x8 a0, a1; ldhl8(pa + k, a0, a1);
    ac = mfma16(a0, b0, ac); ac = mfma16(a1, b0, ac);
    ah = mfma16(a0, b1, ah); ah = mfma16(a1, b1, ah);
  }

  // split-K reduction through LDS
  #pragma unroll
  for (int r = 0; r < 4; ++r) {
    red[wave][r][lane]     = ac[r];
    red[wave][4 + r][lane] = ah[r];
  }
  __syncthreads();
  if (kc == 0) {
    #pragma unroll
    for (int p = 1; p < 4; ++p) {
      const int w2 = p * 4 + mquad;
      #pragma unroll
      for (int r = 0; r < 4; ++r) {
        ac[r] += red[w2][r][lane];
        ah[r] += red[w2][4 + r][lane];
      }
    }
    const int ne = n0 + l15;
    if (ne < Hh) {
      const int act = g_act[e], leaf = g_leaf[e];
      const unsigned* pi = hl + (size_t)src * SLOT;
      unsigned* pj = hl + (size_t)dst * SLOT;
      #pragma unroll
      for (int r = 0; r < 4; ++r) {
        int me = mquad * 16 + quad * 4 + r;
        size_t idx = (size_t)me * HP + ne;
        float cj = sigm(ac[r]);
        float av = actf(act, ah[r]);
        unsigned wi = ldw(pi + idx);
        float hi_v = bf2f((u16)(wi >> 16)) + bf2f((u16)(wi & 0xFFFFu));
        float hj = sanf(cj * av + (1.0f - ldf(c0b + idx)) * hi_v);  // blend uses c0 (!)
        u16 hb = f2bf(hj);
        u16 lb = f2bf(hj - bf2f(hb));
        stw(pj + idx, ((unsigned)hb << 16) | lb);
        if (leaf) atomicAdd(outb + (size_t)(t * Bb + me) * HP + ne, hj);
      }
    }
  }
}

// ---------------------------------------------------------------------------
// Persistent scan: all 64 timesteps, 6 gbar-separated phases each.
// ---------------------------------------------------------------------------
template<bool CB>
__global__ void __launch_bounds__(STPB) scan_kernel(
    const int* __restrict__ inputs, const float* __restrict__ emb,
    const void* __restrict__ wxh, const float* __restrict__ bxh,
    const void* __restrict__ wxc, const float* __restrict__ bxc,
    const void* __restrict__ Wh, const void* __restrict__ Wc,
    unsigned* __restrict__ hl, float* __restrict__ c0b,
    float* __restrict__ outb, unsigned* __restrict__ arr)
{
  __shared__ float red[16][8][64];      // 32 KB
  const int bid = blockIdx.x;
  unsigned ep = 0;

  for (int t = 0; t < Tt; ++t) {
    if (bid < NTILE)
      lev0_body<CB>(bid, t, inputs, emb, wxh, bxh, wxc, bxc, hl, c0b, red);
    gbar(arr, ++ep);
    if (bid < 2 * NTILE) edge_body<CB>(bid, 0, t, Wh, Wc, hl, c0b, outb, red);
    gbar(arr, ++ep);
    if (bid < 3 * NTILE) edge_body<CB>(bid, 2, t, Wh, Wc, hl, c0b, outb, red);
    gbar(arr, ++ep);
    if (bid < 2 * NTILE) edge_body<CB>(bid, 5, t, Wh, Wc, hl, c0b, outb, red);
    gbar(arr, ++ep);
    if (bid < 2 * NTILE) edge_body<CB>(bid, 7, t, Wh, Wc, hl, c0b, outb, red);
    gbar(arr, ++ep);
    if (bid < 2 * NTILE) edge_body<CB>(bid, 9, t, Wh, Wc, hl, c0b, outb, red);
    gbar(arr, ++ep);
  }
}

// ---------------------------------------------------------------------------
// Fallback multi-launch kernels (round-5 behavior; kernel boundary = sync).
// ---------------------------------------------------------------------------
template<bool CB>
__global__ void __launch_bounds__(STPB) lev0_kernel(
    int t, const int* __restrict__ inputs, const float* __restrict__ emb,
    const void* __restrict__ wxh, const float* __restrict__ bxh,
    const void* __restrict__ wxc, const float* __restrict__ bxc,
    unsigned* __restrict__ hl, float* __restrict__ c0b)
{
  __shared__ float red[16][8][64];
  lev0_body<CB>(blockIdx.x, t, inputs, emb, wxh, bxh, wxc, bxc, hl, c0b, red);
}

template<bool CB>
__global__ void __launch_bounds__(STPB) edge_kernel(
    int e0, int t, const void* __restrict__ Wh, const void* __restrict__ Wc,
    unsigned* __restrict__ hl, const float* __restrict__ c0b,
    float* __restrict__ outb)
{
  __shared__ float red[16][8][64];
  edge_body<CB>(blockIdx.x, e0, t, Wh, Wc, hl, c0b, outb, red);
}

// fp32 leaf sums (in d_out) -> bf16 * (1/6) into ws.obf; pads stay zero.
__global__ void __launch_bounds__(TPB) cvt_kernel(const float* __restrict__ outb,
                                                  u16* __restrict__ obf) {
  size_t i = ((size_t)blockIdx.x * TPB + threadIdx.x) * 4;
  float4 v = *(const float4*)(outb + i);
  const float s = 1.0f / 6.0f;
  obf[i + 0] = f2bf(sanf(v.x * s));
  obf[i + 1] = f2bf(sanf(v.y * s));
  obf[i + 2] = f2bf(sanf(v.z * s));
  obf[i + 3] = f2bf(sanf(v.w * s));
}

// decoded[4096,10000] = out @ dec_w.T + dec_b, f32 out. 64x64 tile per WG.
__global__ void __launch_bounds__(TPB) decode_kernel(
    const u16* __restrict__ obf, const float* __restrict__ decw,
    const float* __restrict__ decb, float* __restrict__ out)
{
  const int tid = threadIdx.x;
  const int lane = tid & 63, wave = tid >> 6;
  const int l15 = lane & 15, quad = lane >> 4;
  const int bm = blockIdx.x % 64;   // consecutive blocks share bn -> B reuse in L2
  const int bn = blockIdx.x / 64;
  const int mrow = bm * 64 + wave * 16 + l15;
  const u16* pa = obf + (size_t)mrow * HP;
  const float* pb[4];
  #pragma unroll
  for (int j = 0; j < 4; ++j) {
    int v = bn * 64 + j * 16 + l15;
    if (v > Vv - 1) v = Vv - 1;
    pb[j] = decw + (size_t)v * Hh;
  }
  f32x4 acc[4];
  #pragma unroll
  for (int j = 0; j < 4; ++j) acc[j] = (f32x4){0.f, 0.f, 0.f, 0.f};
  const int koff = quad * 8;
  #pragma unroll 2
  for (int c = 0; c < 31; ++c) {
    int k = c * 32 + koff;
    bf16x8 a = ld8(pa + k);
    #pragma unroll
    for (int j = 0; j < 4; ++j) acc[j] = mfma16(a, cvt8(pb[j] + k), acc[j]);
  }
  { // tail: A covers zeroed pads (in-bounds); mask B (dec_w row end)
    int k = 992 + koff;
    bf16x8 a = ld8(pa + k);
    bf16x8 z = {0, 0, 0, 0, 0, 0, 0, 0};
    #pragma unroll
    for (int j = 0; j < 4; ++j) {
      bf16x8 b = z;
      if (quad == 0) b = cvt8(pb[j] + k);
      acc[j] = mfma16(a, b, acc[j]);
    }
  }
  #pragma unroll
  for (int j = 0; j < 4; ++j) {
    int ne = bn * 64 + j * 16 + l15;
    if (ne < Vv) {
      float bv = sanf(decb[ne]);
      #pragma unroll
      for (int r = 0; r < 4; ++r) {
        int me = bm * 64 + wave * 16 + quad * 4 + r;
        out[(size_t)me * Vv + ne] = acc[j][r] + bv;
      }
    }
  }
}

extern "C" void kernel_launch(void* const* d_in, const int* in_sizes, int n_in,
                              void* d_out, int out_size, void* d_ws, size_t ws_size,
                              hipStream_t stream) {
  const int*   inputs = (const int*)d_in[0];
  const float* hidden = (const float*)d_in[1];
  const float* emb    = (const float*)d_in[2];
  const float* wxh    = (const float*)d_in[3];
  const float* bxh    = (const float*)d_in[4];
  const float* wxc    = (const float*)d_in[5];
  const float* bxc    = (const float*)d_in[6];
  const float* Wh     = (const float*)d_in[7];
  const float* Wc     = (const float*)d_in[8];
  const float* decw   = (const float*)d_in[9];
  const float* decb   = (const float*)d_in[10];

  char* ws = (char*)d_ws;
  unsigned* hl  = (unsigned*)(ws);
  float*    c0b = (float*)(ws + OFF_C0);
  u16*      obf = (u16*)(ws + OFF_OBF);
  unsigned* arr = (unsigned*)(ws + OFF_OBF);  // barrier region, overwritten by cvt
  float*    outb = (float*)d_out;   // fp32 leaf sums, consumed before decode

  const bool cached = (ws_size >= (size_t)WS_CACHED);
  u16* wxhb = (u16*)(ws + OFF_WC + WC_WXH);
  u16* wxcb = (u16*)(ws + OFF_WC + WC_WXC);
  u16* Whb  = (u16*)(ws + OFF_WC + WC_WH);
  u16* Wcb  = (u16*)(ws + OFF_WC + WC_WCC);

  // zero hl (pads must be 0) + c0 + barrier arr/rel, and leaf-sum region
  hipMemsetAsync(ws, 0, OFF_OBF, stream);
  hipMemsetAsync(ws + OFF_OBF, 0, 32768, stream);
  hipMemsetAsync(d_out, 0, OUTB_BYTES, stream);

  if (cached) {
    wcvt_kernel<<<(2000000 / 4 + TPB - 1) / TPB, TPB, 0, stream>>>(wxh, wxhb, 2000000);
    wcvt_kernel<<<(2000000 / 4 + TPB - 1) / TPB, TPB, 0, stream>>>(wxc, wxcb, 2000000);
    wcvt_kernel<<<(11000000 / 4 + TPB - 1) / TPB, TPB, 0, stream>>>(Wh, Whb, 11000000);
    wcvt_kernel<<<(11000000 / 4 + TPB - 1) / TPB, TPB, 0, stream>>>(Wc, Wcb, 11000000);
  }
  stage_kernel<<<Bb, TPB, 0, stream>>>(hidden, hl);

  const void* a_wxh = cached ? (const void*)wxhb : (const void*)wxh;
  const void* a_wxc = cached ? (const void*)wxcb : (const void*)wxc;
  const void* a_Wh  = cached ? (const void*)Whb  : (const void*)Wh;
  const void* a_Wc  = cached ? (const void*)Wcb  : (const void*)Wc;
  void* ka[12] = {(void*)&inputs, (void*)&emb, (void*)&a_wxh, (void*)&bxh,
                  (void*)&a_wxc, (void*)&bxc, (void*)&a_Wh, (void*)&a_Wc,
                  (void*)&hl, (void*)&c0b, (void*)&outb, (void*)&arr};
  dim3 sgrid(GPB), sblk(STPB);
  hipError_t ce = cached
    ? hipLaunchCooperativeKernel(scan_kernel<true>,  sgrid, sblk, ka, 0, stream)
    : hipLaunchCooperativeKernel(scan_kernel<false>, sgrid, sblk, ka, 0, stream);

  if (ce != hipSuccess) {
    (void)hipGetLastError();   // clear sticky error; fall back to multi-launch
    static const int lev_off[5] = {0, 2, 5, 7, 9};
    static const int lev_cnt[5] = {2, 3, 2, 2, 2};
    for (int t = 0; t < Tt; ++t) {
      if (cached) {
        lev0_kernel<true><<<NTILE, STPB, 0, stream>>>(t, inputs, emb, wxhb, bxh,
                                                      wxcb, bxc, hl, c0b);
        for (int lev = 0; lev < 5; ++lev)
          edge_kernel<true><<<lev_cnt[lev] * NTILE, STPB, 0, stream>>>(
              lev_off[lev], t, Whb, Wcb, hl, c0b, outb);
      } else {
        lev0_kernel<false><<<NTILE, STPB, 0, stream>>>(t, inputs, emb, wxh, bxh,
                                                       wxc, bxc, hl, c0b);
        for (int lev = 0; lev < 5; ++lev)
          edge_kernel<false><<<lev_cnt[lev] * NTILE, STPB, 0, stream>>>(
              lev_off[lev], t, Wh, Wc, hl, c0b, outb);
      }
    }
  }

  cvt_kernel<<<(Tt * Bb * HP) / (TPB * 4), TPB, 0, stream>>>(outb, obf);
  decode_kernel<<<64 * 157, TPB, 0, stream>>>(obf, decw, decb, (float*)d_out);
}